// Round 7
// baseline (65.402 us; speedup 1.0000x reference)
//
#include <hip/hip_runtime.h>
#include <hip/hip_bf16.h>
#include <stdint.h>

// pooled[b,i,:] = bias + sum_{j!=i} W_cell(b,i,j) . hid[b,j,:]
// R7: max-TLP formulation. gp_main blocks are ONE wave (64 thr), grid
// NCHUNK*64*4 = 4096 blocks (16 waves/CU resident), zero barriers, zero
// cross-wave LDS. Per wave: (b, chunk of CPB=4 cells, 32-ho slice w):
//   stage-1: z(64 j x 32 ho) = hid_b @ W_c^T   (32 MFMA; A,B frags from L2)
//   z -> wave-private 4KB LDS (XOR-swizzle), transpose read
//   stage-2: acc(64 i x 32 ho) += mask @ z     (16 MFMA; mask from cellt bytes)
// Shared prep (one kernel): W->bf16 [c][hg][ho][e], hid->bf16, cell table.

typedef __attribute__((ext_vector_type(8))) short bf16x8;
typedef __attribute__((ext_vector_type(4))) float f32x4;
typedef unsigned int u32;

#define NCHUNK 16  // cell chunks
#define CPB 4      // cells per chunk

__device__ inline unsigned short bf16bits(float x) {
    __hip_bfloat16 h = __float2bfloat16(x);
    return *reinterpret_cast<unsigned short*>(&h);
}

// ---- prep: 384 blocks x 256 thr ----
//  blocks [0,256):   wconv  (c = bid>>2, ho-quarter q = bid&3)
//  blocks [256,320): cell table for b = bid-256
//  blocks [320,384): hid -> bf16 for b = bid-320
__global__ __launch_bounds__(256)
void gp_prep(const float* __restrict__ W, const float* __restrict__ pos,
             const float* __restrict__ hid,
             __hip_bfloat16* __restrict__ Wb,      // [64][16][128][8]
             unsigned char* __restrict__ cellt_g,  // [64][64][64]
             __hip_bfloat16* __restrict__ Hb)      // [4096][128]
{
    const int bid = blockIdx.x, t = threadIdx.x;
    if (bid < 256) {
        __shared__ __attribute__((aligned(16))) __hip_bfloat16 Wl[32][136];
        const int c = bid >> 2, q = bid & 3;
        #pragma unroll
        for (int it = 0; it < 4; ++it) {
            int idx = it * 256 + t;           // 1024 float4s
            int r = idx >> 5, k4 = idx & 31;
            float4 v = *(const float4*)(W + (size_t)(q * 32 + r) * 8192 + c * 128 + k4 * 4);
            __hip_bfloat16* d = &Wl[r][k4 * 4];
            d[0] = __float2bfloat16(v.x); d[1] = __float2bfloat16(v.y);
            d[2] = __float2bfloat16(v.z); d[3] = __float2bfloat16(v.w);
        }
        __syncthreads();
        #pragma unroll
        for (int it = 0; it < 2; ++it) {
            int idx = it * 256 + t;           // 512: hg(16) x hol(32)
            int hg = idx >> 5, hol = idx & 31;
            bf16x8 v = *(const bf16x8*)&Wl[hol][hg * 8];
            *(bf16x8*)(Wb + (size_t)c * 16384 + hg * 1024 + (q * 32 + hol) * 8) = v;
        }
    } else if (bid < 320) {
        __shared__ float ps[128];
        const int b = bid - 256;
        if (t < 128) ps[t] = pos[(size_t)b * 128 + t];
        __syncthreads();
        #pragma unroll
        for (int qq = 0; qq < 16; ++qq) {
            int idx = qq * 256 + t;           // 4096: i x j
            int i = idx >> 6, j = idx & 63;
            float rx = ps[j * 2 + 0] - ps[i * 2 + 0];
            float ry = ps[j * 2 + 1] - ps[i * 2 + 1];
            int gx = (int)((rx + 2.0f) * 2.0f);
            int gy = (int)((ry + 2.0f) * 2.0f);
            gx = gx < 0 ? 0 : (gx > 7 ? 7 : gx);
            gy = gy < 0 ? 0 : (gy > 7 ? 7 : gy);
            cellt_g[(size_t)b * 4096 + idx] =
                (i == j) ? 255 : (unsigned char)(gx * 8 + gy);
        }
    } else {
        const int b = bid - 320;
        #pragma unroll
        for (int qq = 0; qq < 8; ++qq) {
            int idx = qq * 256 + t;           // 2048 float4s
            float4 v = *(const float4*)(hid + (size_t)b * 8192 + idx * 4);
            union { unsigned short us[4]; uint2 u; } pk;
            pk.us[0] = bf16bits(v.x); pk.us[1] = bf16bits(v.y);
            pk.us[2] = bf16bits(v.z); pk.us[3] = bf16bits(v.w);
            *(uint2*)(Hb + (size_t)b * 8192 + idx * 4) = pk.u;
        }
    }
}

// ---- main: grid = NCHUNK*64*4 blocks of ONE wave; no barriers ----
__global__ __launch_bounds__(64, 4)
void gp_main(const __hip_bfloat16* __restrict__ Hb,
             const unsigned char* __restrict__ cellt_g,
             const __hip_bfloat16* __restrict__ Wb,
             float* __restrict__ partial)
{
    __shared__ u32 zscr[1024];   // wave-private (1 wave/block), 4KB

    const int x = blockIdx.x;
    const int w = x & 3;                 // ho slice [w*32, w*32+32)
    const int b = (x >> 2) & 63;
    const int chunk = x >> 8;            // 0..NCHUNK-1
    const int lane = threadIdx.x;
    const int l15 = lane & 15, kg = lane >> 4;

    // cellt bytes for stage-2 mask frags: cs[mt][ks2] = 8 bytes (i=mt*16+l15, j=ks2*32+kg*8..)
    uint2 cs[4][2];
    #pragma unroll
    for (int mt = 0; mt < 4; ++mt)
        #pragma unroll
        for (int ks2 = 0; ks2 < 2; ++ks2)
            cs[mt][ks2] = *(const uint2*)(cellt_g + (size_t)b * 4096 +
                                          (mt * 16 + l15) * 64 + ks2 * 32 + kg * 8);

    // hid A-frags from L2: a[jt][ks], row j=jt*16+l15, k=(ks*4+kg)*8..+8
    bf16x8 a[4][4];
    #pragma unroll
    for (int jt = 0; jt < 4; ++jt)
        #pragma unroll
        for (int ks = 0; ks < 4; ++ks)
            a[jt][ks] = *(const bf16x8*)(Hb + (size_t)b * 8192 +
                                         (jt * 16 + l15) * 128 + (ks * 4 + kg) * 8);

    f32x4 acc[4][2];
    #pragma unroll
    for (int mt = 0; mt < 4; ++mt) {
        acc[mt][0] = (f32x4){0.f, 0.f, 0.f, 0.f};
        acc[mt][1] = (f32x4){0.f, 0.f, 0.f, 0.f};
    }

    #pragma unroll
    for (int cc = 0; cc < CPB; ++cc) {
        const int c = chunk * CPB + cc;

        // W B-frags from L2 (L2-resident 2MB): col ho=w*32+fh*16+l15, k=(ks*4+kg)*8..
        bf16x8 wf[4][2];
        #pragma unroll
        for (int ks = 0; ks < 4; ++ks)
            #pragma unroll
            for (int fh = 0; fh < 2; ++fh)
                wf[ks][fh] = *(const bf16x8*)(Wb + (size_t)c * 16384 +
                    ((ks * 4 + kg) * 128 + w * 32 + fh * 16 + l15) * 8);

        // stage-1: z[jt][fh] = hid(j x h) @ W_c^T(h x ho), 32 MFMA
        f32x4 z[4][2];
        #pragma unroll
        for (int jt = 0; jt < 4; ++jt) {
            z[jt][0] = (f32x4){0.f, 0.f, 0.f, 0.f};
            z[jt][1] = (f32x4){0.f, 0.f, 0.f, 0.f};
        }
        #pragma unroll
        for (int ks = 0; ks < 4; ++ks)
            #pragma unroll
            for (int jt = 0; jt < 4; ++jt) {
                z[jt][0] = __builtin_amdgcn_mfma_f32_16x16x32_bf16(a[jt][ks], wf[ks][0], z[jt][0], 0, 0, 0);
                z[jt][1] = __builtin_amdgcn_mfma_f32_16x16x32_bf16(a[jt][ks], wf[ks][1], z[jt][1], 0, 0, 0);
            }

        // pack z -> zscr (u32 = bf16 pair (j even, j odd)); D: col=l15=ho, row j
        // jp = j/2; addr32 = (jp*32 + hol) ^ (((jp>>2)&3)<<3)   [R6-verified]
        #pragma unroll
        for (int jt = 0; jt < 4; ++jt)
            #pragma unroll
            for (int fh = 0; fh < 2; ++fh) {
                u32 p0 = (u32)bf16bits(z[jt][fh][0]) | ((u32)bf16bits(z[jt][fh][1]) << 16);
                u32 p1 = (u32)bf16bits(z[jt][fh][2]) | ((u32)bf16bits(z[jt][fh][3]) << 16);
                int X = ((jt * 2 + (kg >> 1)) & 3) << 3;
                int a32 = (((jt * 8 + kg * 2) * 32) + fh * 16 + l15) ^ X;
                zscr[a32] = p0;
                zscr[a32 + 32] = p1;
            }

        // transpose read: b2[ks2][fh], k=j=ks2*32+kg*8+e   [R6-verified]
        bf16x8 b2[2][2];
        #pragma unroll
        for (int ks2 = 0; ks2 < 2; ++ks2)
            #pragma unroll
            for (int fh = 0; fh < 2; ++fh) {
                int base = (((ks2 * 16 + kg * 4) * 32) + fh * 16 + l15) ^ (kg << 3);
                union { u32 wd[4]; bf16x8 v; } r;
                r.wd[0] = zscr[base];
                r.wd[1] = zscr[base + 32];
                r.wd[2] = zscr[base + 64];
                r.wd[3] = zscr[base + 96];
                b2[ks2][fh] = r.v;
            }

        // stage-2: acc(i,ho) += mask(i x j) @ z(j x ho); mask frags in regs
        #pragma unroll
        for (int mt = 0; mt < 4; ++mt) {
            #pragma unroll
            for (int ks2 = 0; ks2 < 2; ++ks2) {
                union { u32 wd[4]; bf16x8 v; } m;
                u32 s0 = cs[mt][ks2].x, s1 = cs[mt][ks2].y;
                #pragma unroll
                for (int k = 0; k < 4; ++k) {
                    u32 s = (k < 2) ? s0 : s1;
                    u32 b0 = (s >> ((k & 1) * 16)) & 0xFFu;
                    u32 b1 = (s >> ((k & 1) * 16 + 8)) & 0xFFu;
                    m.wd[k] = (b0 == (u32)c ? 0x3F80u : 0u) | (b1 == (u32)c ? 0x3F800000u : 0u);
                }
                acc[mt][0] = __builtin_amdgcn_mfma_f32_16x16x32_bf16(m.v, b2[ks2][0], acc[mt][0], 0, 0, 0);
                acc[mt][1] = __builtin_amdgcn_mfma_f32_16x16x32_bf16(m.v, b2[ks2][1], acc[mt][1], 0, 0, 0);
            }
        }
    }

    // epilogue: partial[chunk][b][i][ho]
    float* pb = partial + (((size_t)chunk * 64 + b) * 64) * 128;
    #pragma unroll
    for (int mt = 0; mt < 4; ++mt)
        #pragma unroll
        for (int fh = 0; fh < 2; ++fh)
            #pragma unroll
            for (int r = 0; r < 4; ++r) {
                int i = mt * 16 + kg * 4 + r;
                int ho = w * 32 + fh * 16 + l15;
                pb[(size_t)i * 128 + ho] = acc[mt][fh][r];
            }
}

// ---- reduce: out = bias + sum_chunk partial  (512 blocks x 256 thr) ----
__global__ __launch_bounds__(256)
void gp_reduce(const float* __restrict__ partial, const float* __restrict__ bias,
               float* __restrict__ out)
{
    int gid = blockIdx.x * 256 + threadIdx.x;  // 131072 float4s
    int ho4 = gid & 31;
    float4 a = *(const float4*)(bias + ho4 * 4);
    #pragma unroll
    for (int ch = 0; ch < NCHUNK; ++ch) {
        float4 v = *(const float4*)(partial + (size_t)ch * 524288 + (size_t)gid * 4);
        a.x += v.x; a.y += v.y; a.z += v.z; a.w += v.w;
    }
    *(float4*)(out + (size_t)gid * 4) = a;
}

extern "C" void kernel_launch(void* const* d_in, const int* in_sizes, int n_in,
                              void* d_out, int out_size, void* d_ws, size_t ws_size,
                              hipStream_t stream)
{
    const float* hid  = (const float*)d_in[0];  // [64,64,128]
    const float* pos  = (const float*)d_in[1];  // [64,64,2]
    const float* W    = (const float*)d_in[2];  // [128,8192]
    const float* bias = (const float*)d_in[3];  // [128]
    float* out = (float*)d_out;

    char* ws = (char*)d_ws;
    __hip_bfloat16* Wb      = (__hip_bfloat16*)(ws);                    // 2 MB
    __hip_bfloat16* Hb      = (__hip_bfloat16*)(ws + (2u << 20));       // 1 MB
    unsigned char*  cellt_g = (unsigned char*) (ws + (3u << 20));       // 256 KB
    float*          partial = (float*)         (ws + (4u << 20));       // 32 MB

    hipLaunchKernelGGL(gp_prep,   dim3(384),             dim3(256), 0, stream,
                       W, pos, hid, Wb, cellt_g, Hb);
    hipLaunchKernelGGL(gp_main,   dim3(NCHUNK * 64 * 4), dim3(64),  0, stream,
                       Hb, cellt_g, Wb, partial);
    hipLaunchKernelGGL(gp_reduce, dim3(512),             dim3(256), 0, stream,
                       partial, bias, out);
}